// Round 8
// baseline (157.650 us; speedup 1.0000x reference)
//
#include <hip/hip_runtime.h>
#include <hip/hip_fp16.h>

// GCNRegressor: x[n,128] --GCNConv(W1)--> relu --GCNConv(W2)--> relu --@Wl+bl--> out[n]
// n=100000, E=1600000, IN=128, HID=64.
// R1-R10: CSR+gather, counting sort, fp16 features, MFMA GEMMs: 2913 -> 171 us.
// R11: 8-rows-per-VMEM gather (wave = 8 groups x 8 lanes, uint4/lane): 41.8us agg.
// R12/R13: dot2 + fewer slots: VALU -25% but dur +3..15%. LESSON: agg is
//      LATENCY-bound; issue all loads back-to-back, no branches in between.
// R14: 2 nodes per wave, software-pipelined (16 VMEM in flight): 162 -> 148.7.
// R15/R16/R17: CSR-build experiments. RULE: every 64B line of a store stream
//      must be filled by ONE block (write amp kills otherwise).
// R18: block-major binned (k_bin fixed, ~10us, off profile) but k_bfill = 54us:
//      binned re-read twice scattered via posmap (4B reads, 7x line amp) +
//      gbase read at stride 788B (1563 lines/block) -> FETCH 47MB.
// R19: (a) posmap holds edge VALUES: binned read ONCE, contiguous per segment,
//      during build; passes A/B go pure-LDS. (b) k_xpose transposes gbase so
//      k_bfill reads two contiguous coalesced rows. FETCH 47 -> ~10MB.

#define SHIFT 9
#define BSZ   (1 << SHIFT)     // 512 nodes per bucket
#define NBMAX 256              // >= nb = 196
#define BIN_CH 1024            // edges per k_bin block (private region)
#define PMAX  12288            // bucket edge capacity (mean 8192, +45 sigma)

using f16x8 = __attribute__((ext_vector_type(8))) _Float16;
using f16x2 = __attribute__((ext_vector_type(2))) _Float16;
using f32x4 = __attribute__((ext_vector_type(4))) float;

// ---- Phase 1: per-block counting sort into private binned region ----
// binned[blk*BIN_CH + ex[bucket] ...] sorted by bucket; gbase[blk*(nb+1)+i] =
// exclusive prefix of this block's bucket counts (row i=nb = chunk total).
// pack: src(17b) | local_node(9b)<<17. Block 0 also zeroes the dummy hs row.
__global__ __launch_bounds__(256) void k_bin(const int* __restrict__ src,
                                             const int* __restrict__ dst,
                                             unsigned* __restrict__ binned,
                                             int* __restrict__ gbase,
                                             __half* __restrict__ hs,
                                             int n, int nb, int E) {
    if (blockIdx.x == 0 && threadIdx.x < 8) {
        uint4 z = {0u, 0u, 0u, 0u};
        reinterpret_cast<uint4*>(hs + ((size_t)n << 6))[threadIdx.x] = z;
    }
    __shared__ int h[NBMAX];
    __shared__ int ex[NBMAX + 1];
    __shared__ int cur[NBMAX];
    __shared__ int stmp[256];
    const int t = threadIdx.x;
    const int blk = blockIdx.x;
    const int beg = blk * BIN_CH;
    for (int i = t; i < NBMAX; i += 256) h[i] = 0;
    __syncthreads();
    const int e4 = beg + t * 4;
    const bool act = e4 < E;               // E % 4 == 0: all-or-nothing per thread
    int4 d4 = {0, 0, 0, 0};
    if (act) {
        d4 = *reinterpret_cast<const int4*>(dst + e4);
        atomicAdd(&h[d4.x >> SHIFT], 1);
        atomicAdd(&h[d4.y >> SHIFT], 1);
        atomicAdd(&h[d4.z >> SHIFT], 1);
        atomicAdd(&h[d4.w >> SHIFT], 1);
    }
    __syncthreads();
    const int hv = (t < nb) ? h[t] : 0;
    stmp[t] = hv;
    __syncthreads();
    for (int off = 1; off < 256; off <<= 1) {
        int u = (t >= off) ? stmp[t - off] : 0;
        __syncthreads();
        stmp[t] += u;
        __syncthreads();
    }
    if (t <= nb) ex[t] = stmp[t] - ((t < nb) ? h[t] : 0);  // t==nb -> chunk total
    __syncthreads();
    if (t < nb) cur[t] = ex[t];
    if (t <= nb) gbase[(size_t)blk * (nb + 1) + t] = ex[t];  // coalesced, private
    __syncthreads();
    if (act) {
        const int4 s4 = *reinterpret_cast<const int4*>(src + e4);
        int b0 = d4.x >> SHIFT, b1 = d4.y >> SHIFT;
        int b2 = d4.z >> SHIFT, b3 = d4.w >> SHIFT;
        int p0 = atomicAdd(&cur[b0], 1);
        int p1 = atomicAdd(&cur[b1], 1);
        int p2 = atomicAdd(&cur[b2], 1);
        int p3 = atomicAdd(&cur[b3], 1);
        binned[beg + p0] = (unsigned)s4.x | ((unsigned)(d4.x & (BSZ - 1)) << 17);
        binned[beg + p1] = (unsigned)s4.y | ((unsigned)(d4.y & (BSZ - 1)) << 17);
        binned[beg + p2] = (unsigned)s4.z | ((unsigned)(d4.z & (BSZ - 1)) << 17);
        binned[beg + p3] = (unsigned)s4.w | ((unsigned)(d4.w & (BSZ - 1)) << 17);
    }
}

// ---- Phase 1.5: transpose gbase[nblk][nb+1] -> gbaseT[nb+1][nblk] so k_bfill
// reads contiguous coalesced rows instead of stride-788B columns. ----
#define TD 32
__global__ __launch_bounds__(256) void k_xpose(const int* __restrict__ gbase,
                                               int* __restrict__ gbaseT,
                                               int nblk, int nbp1) {
    __shared__ int tile[TD][TD + 1];
    const int ctiles = (nbp1 + TD - 1) / TD;
    const int bx = blockIdx.x % ctiles;     // bucket-dim tile
    const int by = blockIdx.x / ctiles;     // blk-dim tile
    const int c0 = bx * TD, r0 = by * TD;
    const int tx = threadIdx.x & 31, ty = threadIdx.x >> 5;
    for (int dy = ty; dy < TD; dy += 8) {
        int r = r0 + dy, c = c0 + tx;
        tile[dy][tx] = (r < nblk && c < nbp1) ? gbase[(size_t)r * nbp1 + c] : 0;
    }
    __syncthreads();
    for (int dy = ty; dy < TD; dy += 8) {
        int r = c0 + dy, c = r0 + tx;       // row = bucket, col = blk
        if (r < nbp1 && c < nblk)
            gbaseT[(size_t)r * nblk + c] = tile[tx][dy];
    }
}

// ---- Phase 2: one block per bucket. Pull this bucket's segments from binned
// ONCE (contiguous per segment) into LDS pedges (VALUES); then count per node,
// scan, write packed rowptr + dinv, place colidx -- all from LDS. ----
// rowptr[g] = (edge_base << 8) | min(deg,255) ; colidx entry = src_byte_off.
__global__ __launch_bounds__(256) void k_bfill(const unsigned* __restrict__ binned,
                                               const int* __restrict__ gbaseT,
                                               int nblk, int nb,
                                               int* __restrict__ rowptr,
                                               int* __restrict__ colidx,
                                               float* __restrict__ dinv, int n) {
    __shared__ unsigned pedges[PMAX];   // 48 KB: packed edge values
    __shared__ int cnt[BSZ];
    __shared__ int nbase[BSZ];
    __shared__ int stmp[256];
    __shared__ int sh_tot;
    const int b = blockIdx.x;
    const int t = threadIdx.x;
    if (t == 0) sh_tot = 0;
    for (int i = t; i < BSZ; i += 256) cnt[i] = 0;
    __syncthreads();
    // segment of bucket b in block blk: binned[blk*BIN_CH + s0 .. s1)
    const int* rowS = gbaseT + (size_t)b * nblk;        // s0 per blk (coalesced)
    const int* rowE = gbaseT + (size_t)(b + 1) * nblk;  // s1 per blk (coalesced)
    int ebeg_part = 0;
    for (int blk = t; blk < nblk; blk += 256) {
        const int s0 = rowS[blk];
        const int s1 = rowE[blk];
        ebeg_part += s0;
        const int c = s1 - s0;
        if (c > 0) {
            int pos = atomicAdd(&sh_tot, c);
            const unsigned* bp = binned + (size_t)blk * BIN_CH + s0;
            for (int k = 0; k < c; ++k)
                if (pos + k < PMAX) pedges[pos + k] = bp[k];
        }
    }
    stmp[t] = ebeg_part;
    __syncthreads();
    for (int off = 128; off; off >>= 1) {
        if (t < off) stmp[t] += stmp[t + off];
        __syncthreads();
    }
    const int ebeg = stmp[0];
    const int ecnt = min(sh_tot, PMAX);
    __syncthreads();
    // pass A: per-node counts (pure LDS)
    for (int j = t; j < ecnt; j += 256)
        atomicAdd(&cnt[pedges[j] >> 17], 1);
    __syncthreads();
    // node scan (512 nodes, 2 per thread)
    int c0 = cnt[2 * t], c1 = cnt[2 * t + 1];
    int s = c0 + c1;
    stmp[t] = s;
    __syncthreads();
    for (int off = 1; off < 256; off <<= 1) {
        int u = (t >= off) ? stmp[t - off] : 0;
        __syncthreads();
        stmp[t] += u;
        __syncthreads();
    }
    const int ex = stmp[t] - s;
    nbase[2 * t] = ex;
    nbase[2 * t + 1] = ex + c0;
    __syncthreads();
    const int gb9 = b << SHIFT;
    for (int j = t; j < BSZ; j += 256) {
        const int g = gb9 + j;
        if (g < n) {
            rowptr[g] = (int)(((unsigned)(ebeg + nbase[j]) << 8) |
                              (unsigned)min(cnt[j], 255));
            dinv[g] = rsqrtf((float)cnt[j] + 1.0f);
        }
        cnt[j] = nbase[j];   // becomes local cursor
    }
    __syncthreads();
    // pass B: place (LDS read; colidx region is bucket-private)
    for (int j = t; j < ecnt; j += 256) {
        const unsigned e = pedges[j];
        const int lo = (int)(e >> 17);
        const int off = atomicAdd(&cnt[lo], 1);
        colidx[ebeg + off] = (int)((e & 0x1FFFFu) << 7);  // byte offset of src row
    }
}

// MFMA GEMM: C16[n,64] = fp16( (A[n,K] @ W[K,64]) * dinv[row] ).
// Block = 256 threads = 4 waves; wave w computes rows rb+w*16..+15, all 64 cols.
template <int K, bool A_FP32>
__global__ __launch_bounds__(256) void k_gemm_mfma(const void* __restrict__ Av,
                                                   const float* __restrict__ W,
                                                   const float* __restrict__ dinv,
                                                   __half* __restrict__ C, int n) {
    constexpr int KP = K + 8;  // padded LDS row stride in halves (16B aligned)
    __shared__ _Float16 Wt[64 * KP];
    const int tid = threadIdx.x;
    for (int i = tid; i < K * 64; i += 256) {
        int k = i >> 6, c = i & 63;
        Wt[c * KP + k] = (_Float16)W[i];
    }
    __syncthreads();

    const int lane = tid & 63;
    const int wv = tid >> 6;
    const int r16 = lane & 15;
    const int kq = lane >> 4;                       // 0..3
    const int rb = blockIdx.x * 64 + wv * 16;
    const int arow = min(rb + r16, n - 1);          // clamped A row for this lane

    f32x4 acc[4] = {{0.f,0.f,0.f,0.f},{0.f,0.f,0.f,0.f},
                    {0.f,0.f,0.f,0.f},{0.f,0.f,0.f,0.f}};

#pragma unroll
    for (int kk = 0; kk < K; kk += 32) {
        f16x8 a;
        if (A_FP32) {
            const float* Ap = (const float*)Av + (size_t)arow * K + kk + kq * 8;
            float4 f0 = *reinterpret_cast<const float4*>(Ap);
            float4 f1 = *reinterpret_cast<const float4*>(Ap + 4);
            a[0] = (_Float16)f0.x; a[1] = (_Float16)f0.y;
            a[2] = (_Float16)f0.z; a[3] = (_Float16)f0.w;
            a[4] = (_Float16)f1.x; a[5] = (_Float16)f1.y;
            a[6] = (_Float16)f1.z; a[7] = (_Float16)f1.w;
        } else {
            const _Float16* Ap = (const _Float16*)Av + (size_t)arow * K + kk + kq * 8;
            a = *reinterpret_cast<const f16x8*>(Ap);
        }
#pragma unroll
        for (int nt = 0; nt < 4; ++nt) {
            f16x8 b = *reinterpret_cast<const f16x8*>(&Wt[(nt * 16 + r16) * KP + kk + kq * 8]);
            acc[nt] = __builtin_amdgcn_mfma_f32_16x16x32_f16(a, b, acc[nt], 0, 0, 0);
        }
    }

#pragma unroll
    for (int r = 0; r < 4; ++r) {
        const int row = rb + kq * 4 + r;
        if (row < n) {
            const float di = dinv[row];
#pragma unroll
            for (int nt = 0; nt < 4; ++nt)
                C[((size_t)row << 6) + nt * 16 + r16] = __float2half(acc[nt][r] * di);
        }
    }
}

// Accumulate 8 fp16 (one uint4) into acc[8] via v_dot2_f32_f16: one VALU op per
// value (convert+add fused, fp32 accumulate). Masks (1,0)/(0,1) keep channels
// separate; exact 1.0-multiply => bit-identical to cvt+add.
__device__ __forceinline__ void dotu4(float acc[8], uint4 u, f16x2 pl, f16x2 ph) {
    union { uint4 u4; f16x2 h[4]; } v;
    v.u4 = u;
    acc[0] = __builtin_amdgcn_fdot2(v.h[0], pl, acc[0], false);
    acc[1] = __builtin_amdgcn_fdot2(v.h[0], ph, acc[1], false);
    acc[2] = __builtin_amdgcn_fdot2(v.h[1], pl, acc[2], false);
    acc[3] = __builtin_amdgcn_fdot2(v.h[1], ph, acc[3], false);
    acc[4] = __builtin_amdgcn_fdot2(v.h[2], pl, acc[4], false);
    acc[5] = __builtin_amdgcn_fdot2(v.h[2], ph, acc[5], false);
    acc[6] = __builtin_amdgcn_fdot2(v.h[3], pl, acc[6], false);
    acc[7] = __builtin_amdgcn_fdot2(v.h[3], ph, acc[7], false);
}

// Fold partial sums across the 8 groups: after this every lane holds the full
// sums for its channel-slice p.
__device__ __forceinline__ void fold8(float acc[8]) {
#pragma unroll
    for (int m = 8; m <= 32; m <<= 1) {
#pragma unroll
        for (int j = 0; j < 8; ++j)
            acc[j] += __shfl_xor(acc[j], m, 64);
    }
}

// 2-node pipelined gather (R14, unchanged). Wave = 8 groups x 8 lanes; each
// group's uint4 load fetches one full 128B row. ALL loads for both nodes
// issued back-to-back (8 colidx dwords, then 8 gather uint4s = 16 VMEM in
// flight); node0's dot2s overlap node1's in-flight gathers. Unconditional 4
// slots per node (deg<=32, ~all nodes; dummy-masked loads broadcast the hot
// zero row). Tail loops only for deg>32 (~1%), after the main dots.
__device__ __forceinline__ void gather_pair(const char* __restrict__ hsb,
                                            const int* __restrict__ colidx,
                                            unsigned pk0, unsigned pk1,
                                            int g, int p, unsigned dum,
                                            float acc0[8], float acc1[8]) {
    const f16x2 pl = {(_Float16)1.0f, (_Float16)0.0f};
    const f16x2 ph = {(_Float16)0.0f, (_Float16)1.0f};
    const int beg0 = (int)(pk0 >> 8), deg0 = (int)(pk0 & 255u);
    const int beg1 = (int)(pk1 >> 8), deg1 = (int)(pk1 & 255u);
    const int t0 = deg0 - g, t1 = deg1 - g;   // slot k valid iff 8*k < t
    const unsigned poff = (unsigned)(p << 4);
    const unsigned dumo = dum + poff;
    const int ia = beg0 + g;
    const int ib = beg1 + g;
    // --- issue all 8 colidx loads (slack past E is safe) ---
    unsigned a0 = (unsigned)colidx[ia]      + poff;
    unsigned a1 = (unsigned)colidx[ia + 8]  + poff;
    unsigned a2 = (unsigned)colidx[ia + 16] + poff;
    unsigned a3 = (unsigned)colidx[ia + 24] + poff;
    unsigned b0 = (unsigned)colidx[ib]      + poff;
    unsigned b1 = (unsigned)colidx[ib + 8]  + poff;
    unsigned b2 = (unsigned)colidx[ib + 16] + poff;
    unsigned b3 = (unsigned)colidx[ib + 24] + poff;
    unsigned oa0 = (0  < t0) ? a0 : dumo;
    unsigned oa1 = (8  < t0) ? a1 : dumo;
    unsigned oa2 = (16 < t0) ? a2 : dumo;
    unsigned oa3 = (24 < t0) ? a3 : dumo;
    unsigned ob0 = (0  < t1) ? b0 : dumo;
    unsigned ob1 = (8  < t1) ? b1 : dumo;
    unsigned ob2 = (16 < t1) ? b2 : dumo;
    unsigned ob3 = (24 < t1) ? b3 : dumo;
    // --- issue all 8 gathers ---
    uint4 ua0 = *reinterpret_cast<const uint4*>(hsb + oa0);
    uint4 ua1 = *reinterpret_cast<const uint4*>(hsb + oa1);
    uint4 ua2 = *reinterpret_cast<const uint4*>(hsb + oa2);
    uint4 ua3 = *reinterpret_cast<const uint4*>(hsb + oa3);
    uint4 ub0 = *reinterpret_cast<const uint4*>(hsb + ob0);
    uint4 ub1 = *reinterpret_cast<const uint4*>(hsb + ob1);
    uint4 ub2 = *reinterpret_cast<const uint4*>(hsb + ob2);
    uint4 ub3 = *reinterpret_cast<const uint4*>(hsb + ob3);
    // --- consume node0 while node1's gathers are still in flight ---
    dotu4(acc0, ua0, pl, ph);
    dotu4(acc0, ua1, pl, ph);
    dotu4(acc0, ua2, pl, ph);
    dotu4(acc0, ua3, pl, ph);
    dotu4(acc1, ub0, pl, ph);
    dotu4(acc1, ub1, pl, ph);
    dotu4(acc1, ub2, pl, ph);
    dotu4(acc1, ub3, pl, ph);
    // --- rare tails (deg > 32), wave-uniform, after the main dots ---
    const int ns0 = (deg0 + 7) >> 3;
    for (int k = 4; k < ns0; k += 4) {
        const int ik = beg0 + 8 * k + g;
        unsigned c0 = (unsigned)colidx[ik]      + poff;
        unsigned c1 = (unsigned)colidx[ik + 8]  + poff;
        unsigned c2 = (unsigned)colidx[ik + 16] + poff;
        unsigned c3 = (unsigned)colidx[ik + 24] + poff;
        const int kb = 8 * k;
        uint4 u0 = *reinterpret_cast<const uint4*>(hsb + ((kb      < t0) ? c0 : dumo));
        uint4 u1 = *reinterpret_cast<const uint4*>(hsb + ((kb + 8  < t0) ? c1 : dumo));
        uint4 u2 = *reinterpret_cast<const uint4*>(hsb + ((kb + 16 < t0) ? c2 : dumo));
        uint4 u3 = *reinterpret_cast<const uint4*>(hsb + ((kb + 24 < t0) ? c3 : dumo));
        dotu4(acc0, u0, pl, ph);
        dotu4(acc0, u1, pl, ph);
        dotu4(acc0, u2, pl, ph);
        dotu4(acc0, u3, pl, ph);
    }
    const int ns1 = (deg1 + 7) >> 3;
    for (int k = 4; k < ns1; k += 4) {
        const int ik = beg1 + 8 * k + g;
        unsigned c0 = (unsigned)colidx[ik]      + poff;
        unsigned c1 = (unsigned)colidx[ik + 8]  + poff;
        unsigned c2 = (unsigned)colidx[ik + 16] + poff;
        unsigned c3 = (unsigned)colidx[ik + 24] + poff;
        const int kb = 8 * k;
        uint4 u0 = *reinterpret_cast<const uint4*>(hsb + ((kb      < t1) ? c0 : dumo));
        uint4 u1 = *reinterpret_cast<const uint4*>(hsb + ((kb + 8  < t1) ? c1 : dumo));
        uint4 u2 = *reinterpret_cast<const uint4*>(hsb + ((kb + 16 < t1) ? c2 : dumo));
        uint4 u3 = *reinterpret_cast<const uint4*>(hsb + ((kb + 24 < t1) ? c3 : dumo));
        dotu4(acc1, u0, pl, ph);
        dotu4(acc1, u1, pl, ph);
        dotu4(acc1, u2, pl, ph);
        dotu4(acc1, u3, pl, ph);
    }
    fold8(acc0);
    fold8(acc1);
}

// conv1 aggregation: out16 = fp16(relu(di*(sum_e hs[src_e] + hs_i) + b)).
// 2 nodes per wave; epilogue once: lanes 0-7 -> node0, lanes 8-15 -> node1.
__global__ __launch_bounds__(256) void k_agg_relu(const __half* __restrict__ hs,
                                                  const int* __restrict__ rowptr,
                                                  const int* __restrict__ colidx,
                                                  const float* __restrict__ dinv,
                                                  const float* __restrict__ b,
                                                  __half* __restrict__ out, int n) {
    const int wv = threadIdx.x >> 6;
    const int i0 = blockIdx.x * 8 + wv * 2;
    const int lane = threadIdx.x & 63;
    if (i0 >= n) return;
    const int i1 = min(i0 + 1, n - 1);
    const int g = lane >> 3, p = lane & 7;
    const int iw = (lane & 8) ? i1 : i0;
    const unsigned pk0 = (unsigned)rowptr[i0];
    const unsigned pk1 = (unsigned)rowptr[i1];
    uint4 su = *reinterpret_cast<const uint4*>(hs + ((size_t)iw << 6) + (p << 3));
    const float di = dinv[iw];
    float acc0[8] = {}, acc1[8] = {};
    gather_pair((const char*)hs, colidx, pk0, pk1, g, p, (unsigned)n << 7,
                acc0, acc1);
    if (lane < 16) {
        const f16x2 pl = {(_Float16)1.0f, (_Float16)0.0f};
        const f16x2 ph = {(_Float16)0.0f, (_Float16)1.0f};
        float a[8];
#pragma unroll
        for (int j = 0; j < 8; ++j) a[j] = (lane & 8) ? acc1[j] : acc0[j];
        dotu4(a, su, pl, ph);
        float4 b0 = *reinterpret_cast<const float4*>(b + (p << 3));
        float4 b1 = *reinterpret_cast<const float4*>(b + (p << 3) + 4);
        __half2 h0 = __halves2half2(__float2half(fmaxf(fmaf(a[0], di, b0.x), 0.f)),
                                    __float2half(fmaxf(fmaf(a[1], di, b0.y), 0.f)));
        __half2 h1 = __halves2half2(__float2half(fmaxf(fmaf(a[2], di, b0.z), 0.f)),
                                    __float2half(fmaxf(fmaf(a[3], di, b0.w), 0.f)));
        __half2 h2 = __halves2half2(__float2half(fmaxf(fmaf(a[4], di, b1.x), 0.f)),
                                    __float2half(fmaxf(fmaf(a[5], di, b1.y), 0.f)));
        __half2 h3 = __halves2half2(__float2half(fmaxf(fmaf(a[6], di, b1.z), 0.f)),
                                    __float2half(fmaxf(fmaf(a[7], di, b1.w), 0.f)));
        uint4 u;
        u.x = *reinterpret_cast<unsigned*>(&h0);
        u.y = *reinterpret_cast<unsigned*>(&h1);
        u.z = *reinterpret_cast<unsigned*>(&h2);
        u.w = *reinterpret_cast<unsigned*>(&h3);
        if (iw < n && (i0 + 1 < n || !(lane & 8)))
            *reinterpret_cast<uint4*>(out + ((size_t)iw << 6) + (p << 3)) = u;
    }
}

// conv2 aggregation + relu + (.@Wl + bl) head, fused. 2 nodes per wave;
// xor-1,2,4 reduce stays within each 8-lane group -> lane0 holds v(node0),
// lane8 holds v(node1).
__global__ __launch_bounds__(256) void k_agg_head(const __half* __restrict__ hs,
                                                  const int* __restrict__ rowptr,
                                                  const int* __restrict__ colidx,
                                                  const float* __restrict__ dinv,
                                                  const float* __restrict__ b2,
                                                  const float* __restrict__ Wl,
                                                  const float* __restrict__ bl,
                                                  float* __restrict__ out, int n) {
    const int wv = threadIdx.x >> 6;
    const int i0 = blockIdx.x * 8 + wv * 2;
    const int lane = threadIdx.x & 63;
    if (i0 >= n) return;
    const int i1 = min(i0 + 1, n - 1);
    const int g = lane >> 3, p = lane & 7;
    const int iw = (lane & 8) ? i1 : i0;
    const unsigned pk0 = (unsigned)rowptr[i0];
    const unsigned pk1 = (unsigned)rowptr[i1];
    uint4 su = *reinterpret_cast<const uint4*>(hs + ((size_t)iw << 6) + (p << 3));
    const float di = dinv[iw];
    float acc0[8] = {}, acc1[8] = {};
    gather_pair((const char*)hs, colidx, pk0, pk1, g, p, (unsigned)n << 7,
                acc0, acc1);
    const f16x2 pl = {(_Float16)1.0f, (_Float16)0.0f};
    const f16x2 ph = {(_Float16)0.0f, (_Float16)1.0f};
    float a[8];
#pragma unroll
    for (int j = 0; j < 8; ++j) a[j] = (lane & 8) ? acc1[j] : acc0[j];
    dotu4(a, su, pl, ph);
    float4 b0 = *reinterpret_cast<const float4*>(b2 + (p << 3));
    float4 b1 = *reinterpret_cast<const float4*>(b2 + (p << 3) + 4);
    float4 w0 = *reinterpret_cast<const float4*>(Wl + (p << 3));
    float4 w1 = *reinterpret_cast<const float4*>(Wl + (p << 3) + 4);
    float v = fmaxf(fmaf(a[0], di, b0.x), 0.f) * w0.x
            + fmaxf(fmaf(a[1], di, b0.y), 0.f) * w0.y
            + fmaxf(fmaf(a[2], di, b0.z), 0.f) * w0.z
            + fmaxf(fmaf(a[3], di, b0.w), 0.f) * w0.w
            + fmaxf(fmaf(a[4], di, b1.x), 0.f) * w1.x
            + fmaxf(fmaf(a[5], di, b1.y), 0.f) * w1.y
            + fmaxf(fmaf(a[6], di, b1.z), 0.f) * w1.z
            + fmaxf(fmaf(a[7], di, b1.w), 0.f) * w1.w;
    v += __shfl_xor(v, 1, 64);
    v += __shfl_xor(v, 2, 64);
    v += __shfl_xor(v, 4, 64);
    if (lane == 0) out[i0] = v + bl[0];
    if (lane == 8 && i0 + 1 < n) out[i1] = v + bl[0];
}

extern "C" void kernel_launch(void* const* d_in, const int* in_sizes, int n_in,
                              void* d_out, int out_size, void* d_ws, size_t ws_size,
                              hipStream_t stream) {
    const float* x  = (const float*)d_in[0];
    const int*   ei = (const int*)d_in[1];
    const float* W1 = (const float*)d_in[2];
    const float* b1 = (const float*)d_in[3];
    const float* W2 = (const float*)d_in[4];
    const float* b2 = (const float*)d_in[5];
    const float* Wl = (const float*)d_in[6];
    const float* bl = (const float*)d_in[7];
    float* out = (float*)d_out;

    const int n = in_sizes[0] / 128;   // 100000
    const int E = in_sizes[1] / 2;     // 1600000
    const int* src = ei;
    const int* dst = ei + E;
    const int nb = (n + BSZ - 1) >> SHIFT;          // 196 buckets
    const int nblk = (E + BIN_CH - 1) / BIN_CH;     // 1563 k_bin blocks

    char* ws = (char*)d_ws;
    size_t o = 0;
    auto alloc = [&](size_t bytes) {
        void* p = ws + o;
        o = (o + bytes + 255) & ~(size_t)255;
        return p;
    };
    float* dinv    = (float*)alloc((size_t)n * 4);
    int*   rowptr  = (int*)  alloc((size_t)(n + 1) * 4);
    int*   colidx  = (int*)  alloc(((size_t)E + 64) * 4);        // +slack for unrolled reads
    int*   gbase   = (int*)  alloc((size_t)nblk * (nb + 1) * 4); // per-block bucket offsets
    int*   gbaseT  = (int*)  alloc((size_t)(nb + 1) * nblk * 4); // transposed
    __half* hs     = (__half*)alloc((size_t)(n + 1) * 64 * 2);   // +1 zeroed dummy row
    __half* bufA   = (__half*)alloc((size_t)n * 64 * 2);         // fp16 relu output
    unsigned* binned = (unsigned*)alloc(((size_t)nblk * BIN_CH) * 4);  // block-major

    // ---- CSR build (block-private counting sort; line-private stores only)
    k_bin<<<nblk, 256, 0, stream>>>(src, dst, binned, gbase, hs, n, nb, E);
    const int ctiles = (nb + 1 + TD - 1) / TD;
    const int rtiles = (nblk + TD - 1) / TD;
    k_xpose<<<ctiles * rtiles, 256, 0, stream>>>(gbase, gbaseT, nblk, nb + 1);
    k_bfill<<<nb, 256, 0, stream>>>(binned, gbaseT, nblk, nb, rowptr, colidx,
                                    dinv, n);

    // ---- conv1 ----
    k_gemm_mfma<128, true><<<(n + 63) / 64, 256, 0, stream>>>(x, W1, dinv, hs, n);
    k_agg_relu<<<(n + 7) / 8, 256, 0, stream>>>(hs, rowptr, colidx, dinv, b1, bufA, n);

    // ---- conv2 + head ----
    k_gemm_mfma<64, false><<<(n + 63) / 64, 256, 0, stream>>>(bufA, W2, dinv, hs, n);
    k_agg_head<<<(n + 7) / 8, 256, 0, stream>>>(hs, rowptr, colidx, dinv, b2, Wl, bl,
                                                out, n);
}

// Round 9
// 133.242 us; speedup vs baseline: 1.1832x; 1.1832x over previous
//
#include <hip/hip_runtime.h>
#include <hip/hip_fp16.h>

// GCNRegressor: x[n,128] --GCNConv(W1)--> relu --GCNConv(W2)--> relu --@Wl+bl--> out[n]
// n=100000, E=1600000, IN=128, HID=64.
// R1-R10: CSR+gather, counting sort, fp16 features, MFMA GEMMs: 2913 -> 171 us.
// R11: 8-rows-per-VMEM gather (wave = 8 groups x 8 lanes, uint4/lane): 41.8us agg.
// R12/R13: dot2 + fewer slots: VALU -25% but dur +3..15%. LESSON: agg is
//      LATENCY-bound; issue all loads back-to-back, no branches in between.
// R14: 2 nodes per wave, software-pipelined (16 VMEM in flight): 162 -> 148.7.
// R15/R16/R17: CSR-build experiments. RULE: every 64B line of a store stream
//      must be filled by ONE block (write amp kills otherwise).
// R18: block-major binned (k_bin fixed ~10us) but k_bfill = 54us (posmap
//      scattered re-reads + strided gbase -> FETCH 47MB).
// R19: edge VALUES to LDS during build + transposed gbase: FETCH 47 -> 22MB
//      but dur UNCHANGED (54us). Not fetch-bound: VALUBusy 4.7%, occ 7.3% --
//      serialized on the single-address sh_tot LDS atomic (1563 RMWs/block) +
//      variable-trip nested copy loops + only 196x4 waves on 256 CUs.
// R20: scan-not-atomics + more waves. Segment dests precomputed by a pairwise
//      Hillis-Steele scan over the 1563 lens (coalesced loads, zero atomics);
//      copy loop is short+independent per thread; 1024-thread blocks (16
//      waves/CU on the 196 active CUs). LDS 63.5KB (PMAX 11776).

#define SHIFT 9
#define BSZ   (1 << SHIFT)     // 512 nodes per bucket
#define NBMAX 256              // >= nb = 196
#define BIN_CH 1024            // edges per k_bin block (private region)
#define PMAX  11776            // bucket edge capacity (mean 8163, +40 sigma)

using f16x8 = __attribute__((ext_vector_type(8))) _Float16;
using f16x2 = __attribute__((ext_vector_type(2))) _Float16;
using f32x4 = __attribute__((ext_vector_type(4))) float;

// ---- Phase 1: per-block counting sort into private binned region ----
// binned[blk*BIN_CH + ex[bucket] ...] sorted by bucket; gbase[blk*(nb+1)+i] =
// exclusive prefix of this block's bucket counts (row i=nb = chunk total).
// pack: src(17b) | local_node(9b)<<17. Block 0 also zeroes the dummy hs row.
__global__ __launch_bounds__(256) void k_bin(const int* __restrict__ src,
                                             const int* __restrict__ dst,
                                             unsigned* __restrict__ binned,
                                             int* __restrict__ gbase,
                                             __half* __restrict__ hs,
                                             int n, int nb, int E) {
    if (blockIdx.x == 0 && threadIdx.x < 8) {
        uint4 z = {0u, 0u, 0u, 0u};
        reinterpret_cast<uint4*>(hs + ((size_t)n << 6))[threadIdx.x] = z;
    }
    __shared__ int h[NBMAX];
    __shared__ int ex[NBMAX + 1];
    __shared__ int cur[NBMAX];
    __shared__ int stmp[256];
    const int t = threadIdx.x;
    const int blk = blockIdx.x;
    const int beg = blk * BIN_CH;
    for (int i = t; i < NBMAX; i += 256) h[i] = 0;
    __syncthreads();
    const int e4 = beg + t * 4;
    const bool act = e4 < E;               // E % 4 == 0: all-or-nothing per thread
    int4 d4 = {0, 0, 0, 0};
    if (act) {
        d4 = *reinterpret_cast<const int4*>(dst + e4);
        atomicAdd(&h[d4.x >> SHIFT], 1);
        atomicAdd(&h[d4.y >> SHIFT], 1);
        atomicAdd(&h[d4.z >> SHIFT], 1);
        atomicAdd(&h[d4.w >> SHIFT], 1);
    }
    __syncthreads();
    const int hv = (t < nb) ? h[t] : 0;
    stmp[t] = hv;
    __syncthreads();
    for (int off = 1; off < 256; off <<= 1) {
        int u = (t >= off) ? stmp[t - off] : 0;
        __syncthreads();
        stmp[t] += u;
        __syncthreads();
    }
    if (t <= nb) ex[t] = stmp[t] - ((t < nb) ? h[t] : 0);  // t==nb -> chunk total
    __syncthreads();
    if (t < nb) cur[t] = ex[t];
    if (t <= nb) gbase[(size_t)blk * (nb + 1) + t] = ex[t];  // coalesced, private
    __syncthreads();
    if (act) {
        const int4 s4 = *reinterpret_cast<const int4*>(src + e4);
        int b0 = d4.x >> SHIFT, b1 = d4.y >> SHIFT;
        int b2 = d4.z >> SHIFT, b3 = d4.w >> SHIFT;
        int p0 = atomicAdd(&cur[b0], 1);
        int p1 = atomicAdd(&cur[b1], 1);
        int p2 = atomicAdd(&cur[b2], 1);
        int p3 = atomicAdd(&cur[b3], 1);
        binned[beg + p0] = (unsigned)s4.x | ((unsigned)(d4.x & (BSZ - 1)) << 17);
        binned[beg + p1] = (unsigned)s4.y | ((unsigned)(d4.y & (BSZ - 1)) << 17);
        binned[beg + p2] = (unsigned)s4.z | ((unsigned)(d4.z & (BSZ - 1)) << 17);
        binned[beg + p3] = (unsigned)s4.w | ((unsigned)(d4.w & (BSZ - 1)) << 17);
    }
}

// ---- Phase 1.5: transpose gbase[nblk][nb+1] -> gbaseT[nb+1][nblk] so k_bfill
// reads contiguous coalesced rows instead of stride-788B columns. ----
#define TD 32
__global__ __launch_bounds__(256) void k_xpose(const int* __restrict__ gbase,
                                               int* __restrict__ gbaseT,
                                               int nblk, int nbp1) {
    __shared__ int tile[TD][TD + 1];
    const int ctiles = (nbp1 + TD - 1) / TD;
    const int bx = blockIdx.x % ctiles;     // bucket-dim tile
    const int by = blockIdx.x / ctiles;     // blk-dim tile
    const int c0 = bx * TD, r0 = by * TD;
    const int tx = threadIdx.x & 31, ty = threadIdx.x >> 5;
    for (int dy = ty; dy < TD; dy += 8) {
        int r = r0 + dy, c = c0 + tx;
        tile[dy][tx] = (r < nblk && c < nbp1) ? gbase[(size_t)r * nbp1 + c] : 0;
    }
    __syncthreads();
    for (int dy = ty; dy < TD; dy += 8) {
        int r = c0 + dy, c = r0 + tx;       // row = bucket, col = blk
        if (r < nbp1 && c < nblk)
            gbaseT[(size_t)r * nblk + c] = tile[tx][dy];
    }
}

// ---- Phase 2: one 1024-thread block per bucket. Zero-atomic build:
// (1) coalesced len load + ebeg reduction, (2) pairwise Hillis-Steele scan
// over 2048-padded lens -> per-segment LDS dest, (3) parallel segment copy
// into pedges, (4) count/scan/place from LDS. ----
// rowptr[g] = (edge_base << 8) | min(deg,255) ; colidx entry = src_byte_off.
__global__ __launch_bounds__(1024) void k_bfill(const unsigned* __restrict__ binned,
                                                const int* __restrict__ gbaseT,
                                                int nblk, int nb,
                                                int* __restrict__ rowptr,
                                                int* __restrict__ colidx,
                                                float* __restrict__ dinv, int n) {
    __shared__ unsigned pedges[PMAX];   // 46 KB: packed edge values
    __shared__ int segarr[2048];        // lens, then exclusive prefix (dest)
    __shared__ int stmp[1024];
    __shared__ int cnt[BSZ];
    __shared__ int nbase[BSZ];
    const int b = blockIdx.x;
    const int t = threadIdx.x;
    const int* rowS = gbaseT + (size_t)b * nblk;        // s0 per blk (coalesced)
    const int* rowE = gbaseT + (size_t)(b + 1) * nblk;  // s1 per blk (coalesced)
    for (int i = t; i < BSZ; i += 1024) cnt[i] = 0;
    // load lens (strided, coalesced) + ebeg partial
    int eb = 0;
    {
        int l0 = 0, l1 = 0;
        if (t < nblk)        { int s0 = rowS[t];        l0 = rowE[t] - s0;        eb += s0; }
        if (t + 1024 < nblk) { int s0 = rowS[t + 1024]; l1 = rowE[t + 1024] - s0; eb += s0; }
        segarr[t] = l0;
        segarr[t + 1024] = l1;
    }
    // ebeg reduction
    stmp[t] = eb;
    __syncthreads();
    for (int off = 512; off; off >>= 1) {
        if (t < off) stmp[t] += stmp[t + off];
        __syncthreads();
    }
    const int ebeg = stmp[0];
    __syncthreads();
    // pairwise exclusive scan over segarr[2048]: thread t owns 2t, 2t+1
    const int a0 = segarr[2 * t];
    const int a1 = segarr[2 * t + 1];
    const int ps = a0 + a1;
    stmp[t] = ps;
    __syncthreads();
    for (int off = 1; off < 1024; off <<= 1) {
        int u = (t >= off) ? stmp[t - off] : 0;
        __syncthreads();
        stmp[t] += u;
        __syncthreads();
    }
    const int ecnt = min(stmp[1023], PMAX);   // bucket total
    const int exp2_ = stmp[t] - ps;
    segarr[2 * t] = exp2_;
    segarr[2 * t + 1] = exp2_ + a0;
    __syncthreads();
    // parallel segment copy (no atomics; dests precomputed)
    for (int blk = t; blk < nblk; blk += 1024) {
        const int s0 = rowS[blk];
        const int c = rowE[blk] - s0;
        const int pos = segarr[blk];
        const unsigned* bp = binned + (size_t)blk * BIN_CH + s0;
        for (int k = 0; k < c; ++k) {
            const int d = pos + k;
            if (d < PMAX) pedges[d] = bp[k];
        }
    }
    __syncthreads();
    // pass A: per-node counts (pure LDS)
    for (int j = t; j < ecnt; j += 1024)
        atomicAdd(&cnt[pedges[j] >> 17], 1);
    __syncthreads();
    // node scan (512 nodes; threads 0-255 own 2 nodes each)
    const int c0 = (t < 256) ? cnt[2 * t] : 0;
    const int c1 = (t < 256) ? cnt[2 * t + 1] : 0;
    const int s2 = c0 + c1;
    stmp[t] = s2;
    __syncthreads();
    for (int off = 1; off < 256; off <<= 1) {
        int u = (t >= off && t < 256) ? stmp[t - off] : 0;
        __syncthreads();
        if (t < 256) stmp[t] += u;
        __syncthreads();
    }
    if (t < 256) {
        const int ex = stmp[t] - s2;
        nbase[2 * t] = ex;
        nbase[2 * t + 1] = ex + c0;
    }
    __syncthreads();
    const int gb9 = b << SHIFT;
    for (int j = t; j < BSZ; j += 1024) {
        const int g = gb9 + j;
        if (g < n) {
            rowptr[g] = (int)(((unsigned)(ebeg + nbase[j]) << 8) |
                              (unsigned)min(cnt[j], 255));
            dinv[g] = rsqrtf((float)cnt[j] + 1.0f);
        }
        cnt[j] = nbase[j];   // becomes local cursor
    }
    __syncthreads();
    // pass B: place (LDS read; colidx region is bucket-private)
    for (int j = t; j < ecnt; j += 1024) {
        const unsigned e = pedges[j];
        const int lo = (int)(e >> 17);
        const int off = atomicAdd(&cnt[lo], 1);
        colidx[ebeg + off] = (int)((e & 0x1FFFFu) << 7);  // byte offset of src row
    }
}

// MFMA GEMM: C16[n,64] = fp16( (A[n,K] @ W[K,64]) * dinv[row] ).
// Block = 256 threads = 4 waves; wave w computes rows rb+w*16..+15, all 64 cols.
template <int K, bool A_FP32>
__global__ __launch_bounds__(256) void k_gemm_mfma(const void* __restrict__ Av,
                                                   const float* __restrict__ W,
                                                   const float* __restrict__ dinv,
                                                   __half* __restrict__ C, int n) {
    constexpr int KP = K + 8;  // padded LDS row stride in halves (16B aligned)
    __shared__ _Float16 Wt[64 * KP];
    const int tid = threadIdx.x;
    for (int i = tid; i < K * 64; i += 256) {
        int k = i >> 6, c = i & 63;
        Wt[c * KP + k] = (_Float16)W[i];
    }
    __syncthreads();

    const int lane = tid & 63;
    const int wv = tid >> 6;
    const int r16 = lane & 15;
    const int kq = lane >> 4;                       // 0..3
    const int rb = blockIdx.x * 64 + wv * 16;
    const int arow = min(rb + r16, n - 1);          // clamped A row for this lane

    f32x4 acc[4] = {{0.f,0.f,0.f,0.f},{0.f,0.f,0.f,0.f},
                    {0.f,0.f,0.f,0.f},{0.f,0.f,0.f,0.f}};

#pragma unroll
    for (int kk = 0; kk < K; kk += 32) {
        f16x8 a;
        if (A_FP32) {
            const float* Ap = (const float*)Av + (size_t)arow * K + kk + kq * 8;
            float4 f0 = *reinterpret_cast<const float4*>(Ap);
            float4 f1 = *reinterpret_cast<const float4*>(Ap + 4);
            a[0] = (_Float16)f0.x; a[1] = (_Float16)f0.y;
            a[2] = (_Float16)f0.z; a[3] = (_Float16)f0.w;
            a[4] = (_Float16)f1.x; a[5] = (_Float16)f1.y;
            a[6] = (_Float16)f1.z; a[7] = (_Float16)f1.w;
        } else {
            const _Float16* Ap = (const _Float16*)Av + (size_t)arow * K + kk + kq * 8;
            a = *reinterpret_cast<const f16x8*>(Ap);
        }
#pragma unroll
        for (int nt = 0; nt < 4; ++nt) {
            f16x8 b = *reinterpret_cast<const f16x8*>(&Wt[(nt * 16 + r16) * KP + kk + kq * 8]);
            acc[nt] = __builtin_amdgcn_mfma_f32_16x16x32_f16(a, b, acc[nt], 0, 0, 0);
        }
    }

#pragma unroll
    for (int r = 0; r < 4; ++r) {
        const int row = rb + kq * 4 + r;
        if (row < n) {
            const float di = dinv[row];
#pragma unroll
            for (int nt = 0; nt < 4; ++nt)
                C[((size_t)row << 6) + nt * 16 + r16] = __float2half(acc[nt][r] * di);
        }
    }
}

// Accumulate 8 fp16 (one uint4) into acc[8] via v_dot2_f32_f16: one VALU op per
// value (convert+add fused, fp32 accumulate). Masks (1,0)/(0,1) keep channels
// separate; exact 1.0-multiply => bit-identical to cvt+add.
__device__ __forceinline__ void dotu4(float acc[8], uint4 u, f16x2 pl, f16x2 ph) {
    union { uint4 u4; f16x2 h[4]; } v;
    v.u4 = u;
    acc[0] = __builtin_amdgcn_fdot2(v.h[0], pl, acc[0], false);
    acc[1] = __builtin_amdgcn_fdot2(v.h[0], ph, acc[1], false);
    acc[2] = __builtin_amdgcn_fdot2(v.h[1], pl, acc[2], false);
    acc[3] = __builtin_amdgcn_fdot2(v.h[1], ph, acc[3], false);
    acc[4] = __builtin_amdgcn_fdot2(v.h[2], pl, acc[4], false);
    acc[5] = __builtin_amdgcn_fdot2(v.h[2], ph, acc[5], false);
    acc[6] = __builtin_amdgcn_fdot2(v.h[3], pl, acc[6], false);
    acc[7] = __builtin_amdgcn_fdot2(v.h[3], ph, acc[7], false);
}

// Fold partial sums across the 8 groups: after this every lane holds the full
// sums for its channel-slice p.
__device__ __forceinline__ void fold8(float acc[8]) {
#pragma unroll
    for (int m = 8; m <= 32; m <<= 1) {
#pragma unroll
        for (int j = 0; j < 8; ++j)
            acc[j] += __shfl_xor(acc[j], m, 64);
    }
}

// 2-node pipelined gather (R14, unchanged). Wave = 8 groups x 8 lanes; each
// group's uint4 load fetches one full 128B row. ALL loads for both nodes
// issued back-to-back (8 colidx dwords, then 8 gather uint4s = 16 VMEM in
// flight); node0's dot2s overlap node1's in-flight gathers. Unconditional 4
// slots per node (deg<=32, ~all nodes; dummy-masked loads broadcast the hot
// zero row). Tail loops only for deg>32 (~1%), after the main dots.
__device__ __forceinline__ void gather_pair(const char* __restrict__ hsb,
                                            const int* __restrict__ colidx,
                                            unsigned pk0, unsigned pk1,
                                            int g, int p, unsigned dum,
                                            float acc0[8], float acc1[8]) {
    const f16x2 pl = {(_Float16)1.0f, (_Float16)0.0f};
    const f16x2 ph = {(_Float16)0.0f, (_Float16)1.0f};
    const int beg0 = (int)(pk0 >> 8), deg0 = (int)(pk0 & 255u);
    const int beg1 = (int)(pk1 >> 8), deg1 = (int)(pk1 & 255u);
    const int t0 = deg0 - g, t1 = deg1 - g;   // slot k valid iff 8*k < t
    const unsigned poff = (unsigned)(p << 4);
    const unsigned dumo = dum + poff;
    const int ia = beg0 + g;
    const int ib = beg1 + g;
    // --- issue all 8 colidx loads (slack past E is safe) ---
    unsigned a0 = (unsigned)colidx[ia]      + poff;
    unsigned a1 = (unsigned)colidx[ia + 8]  + poff;
    unsigned a2 = (unsigned)colidx[ia + 16] + poff;
    unsigned a3 = (unsigned)colidx[ia + 24] + poff;
    unsigned b0 = (unsigned)colidx[ib]      + poff;
    unsigned b1 = (unsigned)colidx[ib + 8]  + poff;
    unsigned b2 = (unsigned)colidx[ib + 16] + poff;
    unsigned b3 = (unsigned)colidx[ib + 24] + poff;
    unsigned oa0 = (0  < t0) ? a0 : dumo;
    unsigned oa1 = (8  < t0) ? a1 : dumo;
    unsigned oa2 = (16 < t0) ? a2 : dumo;
    unsigned oa3 = (24 < t0) ? a3 : dumo;
    unsigned ob0 = (0  < t1) ? b0 : dumo;
    unsigned ob1 = (8  < t1) ? b1 : dumo;
    unsigned ob2 = (16 < t1) ? b2 : dumo;
    unsigned ob3 = (24 < t1) ? b3 : dumo;
    // --- issue all 8 gathers ---
    uint4 ua0 = *reinterpret_cast<const uint4*>(hsb + oa0);
    uint4 ua1 = *reinterpret_cast<const uint4*>(hsb + oa1);
    uint4 ua2 = *reinterpret_cast<const uint4*>(hsb + oa2);
    uint4 ua3 = *reinterpret_cast<const uint4*>(hsb + oa3);
    uint4 ub0 = *reinterpret_cast<const uint4*>(hsb + ob0);
    uint4 ub1 = *reinterpret_cast<const uint4*>(hsb + ob1);
    uint4 ub2 = *reinterpret_cast<const uint4*>(hsb + ob2);
    uint4 ub3 = *reinterpret_cast<const uint4*>(hsb + ob3);
    // --- consume node0 while node1's gathers are still in flight ---
    dotu4(acc0, ua0, pl, ph);
    dotu4(acc0, ua1, pl, ph);
    dotu4(acc0, ua2, pl, ph);
    dotu4(acc0, ua3, pl, ph);
    dotu4(acc1, ub0, pl, ph);
    dotu4(acc1, ub1, pl, ph);
    dotu4(acc1, ub2, pl, ph);
    dotu4(acc1, ub3, pl, ph);
    // --- rare tails (deg > 32), wave-uniform, after the main dots ---
    const int ns0 = (deg0 + 7) >> 3;
    for (int k = 4; k < ns0; k += 4) {
        const int ik = beg0 + 8 * k + g;
        unsigned c0 = (unsigned)colidx[ik]      + poff;
        unsigned c1 = (unsigned)colidx[ik + 8]  + poff;
        unsigned c2 = (unsigned)colidx[ik + 16] + poff;
        unsigned c3 = (unsigned)colidx[ik + 24] + poff;
        const int kb = 8 * k;
        uint4 u0 = *reinterpret_cast<const uint4*>(hsb + ((kb      < t0) ? c0 : dumo));
        uint4 u1 = *reinterpret_cast<const uint4*>(hsb + ((kb + 8  < t0) ? c1 : dumo));
        uint4 u2 = *reinterpret_cast<const uint4*>(hsb + ((kb + 16 < t0) ? c2 : dumo));
        uint4 u3 = *reinterpret_cast<const uint4*>(hsb + ((kb + 24 < t0) ? c3 : dumo));
        dotu4(acc0, u0, pl, ph);
        dotu4(acc0, u1, pl, ph);
        dotu4(acc0, u2, pl, ph);
        dotu4(acc0, u3, pl, ph);
    }
    const int ns1 = (deg1 + 7) >> 3;
    for (int k = 4; k < ns1; k += 4) {
        const int ik = beg1 + 8 * k + g;
        unsigned c0 = (unsigned)colidx[ik]      + poff;
        unsigned c1 = (unsigned)colidx[ik + 8]  + poff;
        unsigned c2 = (unsigned)colidx[ik + 16] + poff;
        unsigned c3 = (unsigned)colidx[ik + 24] + poff;
        const int kb = 8 * k;
        uint4 u0 = *reinterpret_cast<const uint4*>(hsb + ((kb      < t1) ? c0 : dumo));
        uint4 u1 = *reinterpret_cast<const uint4*>(hsb + ((kb + 8  < t1) ? c1 : dumo));
        uint4 u2 = *reinterpret_cast<const uint4*>(hsb + ((kb + 16 < t1) ? c2 : dumo));
        uint4 u3 = *reinterpret_cast<const uint4*>(hsb + ((kb + 24 < t1) ? c3 : dumo));
        dotu4(acc1, u0, pl, ph);
        dotu4(acc1, u1, pl, ph);
        dotu4(acc1, u2, pl, ph);
        dotu4(acc1, u3, pl, ph);
    }
    fold8(acc0);
    fold8(acc1);
}

// conv1 aggregation: out16 = fp16(relu(di*(sum_e hs[src_e] + hs_i) + b)).
// 2 nodes per wave; epilogue once: lanes 0-7 -> node0, lanes 8-15 -> node1.
__global__ __launch_bounds__(256) void k_agg_relu(const __half* __restrict__ hs,
                                                  const int* __restrict__ rowptr,
                                                  const int* __restrict__ colidx,
                                                  const float* __restrict__ dinv,
                                                  const float* __restrict__ b,
                                                  __half* __restrict__ out, int n) {
    const int wv = threadIdx.x >> 6;
    const int i0 = blockIdx.x * 8 + wv * 2;
    const int lane = threadIdx.x & 63;
    if (i0 >= n) return;
    const int i1 = min(i0 + 1, n - 1);
    const int g = lane >> 3, p = lane & 7;
    const int iw = (lane & 8) ? i1 : i0;
    const unsigned pk0 = (unsigned)rowptr[i0];
    const unsigned pk1 = (unsigned)rowptr[i1];
    uint4 su = *reinterpret_cast<const uint4*>(hs + ((size_t)iw << 6) + (p << 3));
    const float di = dinv[iw];
    float acc0[8] = {}, acc1[8] = {};
    gather_pair((const char*)hs, colidx, pk0, pk1, g, p, (unsigned)n << 7,
                acc0, acc1);
    if (lane < 16) {
        const f16x2 pl = {(_Float16)1.0f, (_Float16)0.0f};
        const f16x2 ph = {(_Float16)0.0f, (_Float16)1.0f};
        float a[8];
#pragma unroll
        for (int j = 0; j < 8; ++j) a[j] = (lane & 8) ? acc1[j] : acc0[j];
        dotu4(a, su, pl, ph);
        float4 b0 = *reinterpret_cast<const float4*>(b + (p << 3));
        float4 b1 = *reinterpret_cast<const float4*>(b + (p << 3) + 4);
        __half2 h0 = __halves2half2(__float2half(fmaxf(fmaf(a[0], di, b0.x), 0.f)),
                                    __float2half(fmaxf(fmaf(a[1], di, b0.y), 0.f)));
        __half2 h1 = __halves2half2(__float2half(fmaxf(fmaf(a[2], di, b0.z), 0.f)),
                                    __float2half(fmaxf(fmaf(a[3], di, b0.w), 0.f)));
        __half2 h2 = __halves2half2(__float2half(fmaxf(fmaf(a[4], di, b1.x), 0.f)),
                                    __float2half(fmaxf(fmaf(a[5], di, b1.y), 0.f)));
        __half2 h3 = __halves2half2(__float2half(fmaxf(fmaf(a[6], di, b1.z), 0.f)),
                                    __float2half(fmaxf(fmaf(a[7], di, b1.w), 0.f)));
        uint4 u;
        u.x = *reinterpret_cast<unsigned*>(&h0);
        u.y = *reinterpret_cast<unsigned*>(&h1);
        u.z = *reinterpret_cast<unsigned*>(&h2);
        u.w = *reinterpret_cast<unsigned*>(&h3);
        if (iw < n && (i0 + 1 < n || !(lane & 8)))
            *reinterpret_cast<uint4*>(out + ((size_t)iw << 6) + (p << 3)) = u;
    }
}

// conv2 aggregation + relu + (.@Wl + bl) head, fused. 2 nodes per wave;
// xor-1,2,4 reduce stays within each 8-lane group -> lane0 holds v(node0),
// lane8 holds v(node1).
__global__ __launch_bounds__(256) void k_agg_head(const __half* __restrict__ hs,
                                                  const int* __restrict__ rowptr,
                                                  const int* __restrict__ colidx,
                                                  const float* __restrict__ dinv,
                                                  const float* __restrict__ b2,
                                                  const float* __restrict__ Wl,
                                                  const float* __restrict__ bl,
                                                  float* __restrict__ out, int n) {
    const int wv = threadIdx.x >> 6;
    const int i0 = blockIdx.x * 8 + wv * 2;
    const int lane = threadIdx.x & 63;
    if (i0 >= n) return;
    const int i1 = min(i0 + 1, n - 1);
    const int g = lane >> 3, p = lane & 7;
    const int iw = (lane & 8) ? i1 : i0;
    const unsigned pk0 = (unsigned)rowptr[i0];
    const unsigned pk1 = (unsigned)rowptr[i1];
    uint4 su = *reinterpret_cast<const uint4*>(hs + ((size_t)iw << 6) + (p << 3));
    const float di = dinv[iw];
    float acc0[8] = {}, acc1[8] = {};
    gather_pair((const char*)hs, colidx, pk0, pk1, g, p, (unsigned)n << 7,
                acc0, acc1);
    const f16x2 pl = {(_Float16)1.0f, (_Float16)0.0f};
    const f16x2 ph = {(_Float16)0.0f, (_Float16)1.0f};
    float a[8];
#pragma unroll
    for (int j = 0; j < 8; ++j) a[j] = (lane & 8) ? acc1[j] : acc0[j];
    dotu4(a, su, pl, ph);
    float4 b0 = *reinterpret_cast<const float4*>(b2 + (p << 3));
    float4 b1 = *reinterpret_cast<const float4*>(b2 + (p << 3) + 4);
    float4 w0 = *reinterpret_cast<const float4*>(Wl + (p << 3));
    float4 w1 = *reinterpret_cast<const float4*>(Wl + (p << 3) + 4);
    float v = fmaxf(fmaf(a[0], di, b0.x), 0.f) * w0.x
            + fmaxf(fmaf(a[1], di, b0.y), 0.f) * w0.y
            + fmaxf(fmaf(a[2], di, b0.z), 0.f) * w0.z
            + fmaxf(fmaf(a[3], di, b0.w), 0.f) * w0.w
            + fmaxf(fmaf(a[4], di, b1.x), 0.f) * w1.x
            + fmaxf(fmaf(a[5], di, b1.y), 0.f) * w1.y
            + fmaxf(fmaf(a[6], di, b1.z), 0.f) * w1.z
            + fmaxf(fmaf(a[7], di, b1.w), 0.f) * w1.w;
    v += __shfl_xor(v, 1, 64);
    v += __shfl_xor(v, 2, 64);
    v += __shfl_xor(v, 4, 64);
    if (lane == 0) out[i0] = v + bl[0];
    if (lane == 8 && i0 + 1 < n) out[i1] = v + bl[0];
}

extern "C" void kernel_launch(void* const* d_in, const int* in_sizes, int n_in,
                              void* d_out, int out_size, void* d_ws, size_t ws_size,
                              hipStream_t stream) {
    const float* x  = (const float*)d_in[0];
    const int*   ei = (const int*)d_in[1];
    const float* W1 = (const float*)d_in[2];
    const float* b1 = (const float*)d_in[3];
    const float* W2 = (const float*)d_in[4];
    const float* b2 = (const float*)d_in[5];
    const float* Wl = (const float*)d_in[6];
    const float* bl = (const float*)d_in[7];
    float* out = (float*)d_out;

    const int n = in_sizes[0] / 128;   // 100000
    const int E = in_sizes[1] / 2;     // 1600000
    const int* src = ei;
    const int* dst = ei + E;
    const int nb = (n + BSZ - 1) >> SHIFT;          // 196 buckets
    const int nblk = (E + BIN_CH - 1) / BIN_CH;     // 1563 k_bin blocks

    char* ws = (char*)d_ws;
    size_t o = 0;
    auto alloc = [&](size_t bytes) {
        void* p = ws + o;
        o = (o + bytes + 255) & ~(size_t)255;
        return p;
    };
    float* dinv    = (float*)alloc((size_t)n * 4);
    int*   rowptr  = (int*)  alloc((size_t)(n + 1) * 4);
    int*   colidx  = (int*)  alloc(((size_t)E + 64) * 4);        // +slack for unrolled reads
    int*   gbase   = (int*)  alloc((size_t)nblk * (nb + 1) * 4); // per-block bucket offsets
    int*   gbaseT  = (int*)  alloc((size_t)(nb + 1) * nblk * 4); // transposed
    __half* hs     = (__half*)alloc((size_t)(n + 1) * 64 * 2);   // +1 zeroed dummy row
    __half* bufA   = (__half*)alloc((size_t)n * 64 * 2);         // fp16 relu output
    unsigned* binned = (unsigned*)alloc(((size_t)nblk * BIN_CH) * 4);  // block-major

    // ---- CSR build (block-private counting sort; line-private stores only)
    k_bin<<<nblk, 256, 0, stream>>>(src, dst, binned, gbase, hs, n, nb, E);
    const int ctiles = (nb + 1 + TD - 1) / TD;
    const int rtiles = (nblk + TD - 1) / TD;
    k_xpose<<<ctiles * rtiles, 256, 0, stream>>>(gbase, gbaseT, nblk, nb + 1);
    k_bfill<<<nb, 1024, 0, stream>>>(binned, gbaseT, nblk, nb, rowptr, colidx,
                                     dinv, n);

    // ---- conv1 ----
    k_gemm_mfma<128, true><<<(n + 63) / 64, 256, 0, stream>>>(x, W1, dinv, hs, n);
    k_agg_relu<<<(n + 7) / 8, 256, 0, stream>>>(hs, rowptr, colidx, dinv, b1, bufA, n);

    // ---- conv2 + head ----
    k_gemm_mfma<64, false><<<(n + 63) / 64, 256, 0, stream>>>(bufA, W2, dinv, hs, n);
    k_agg_head<<<(n + 7) / 8, 256, 0, stream>>>(hs, rowptr, colidx, dinv, b2, Wl, bl,
                                                out, n);
}